// Round 4
// baseline (952.353 us; speedup 1.0000x reference)
//
#include <hip/hip_runtime.h>
#include <stdint.h>

// 1 = JAX >= 0.5 default (jax_threefry_partitionable=True); 0 = legacy scheme.
#define JAX_PARTITIONABLE 1

constexpr int kC = 64;          // channels (= NMF rows T)
constexpr int kS = 65536;       // spatial 16*64*64 (= NMF cols M)
constexpr int kL = 8;           // NMF rank
constexpr int kIters = 50;
constexpr int kBlocks = 512;    // 2 blocks/CU -> barrier spin overlaps compute
constexpr int kThreads = 512;
constexpr int kCols = 128;      // columns per block
constexpr int kGroups = 16;     // stage-1 reduction groups (32 blocks/group)
constexpr int kEntries = 576;   // 512 (VH^T) + 64 (HH^T)
constexpr int kPitch = 132;     // LDS row pitch (132%32==4; 16B-aligned rows)
constexpr float kEps = 1.1920929e-07f;

#define AGENT __HIP_MEMORY_SCOPE_AGENT

struct Ctl {
  unsigned root;  unsigned pad0[31];     // barrier root counter
  unsigned leaf[32][32];                 // 32 leaf counters, 128 B apart
  float mean_sum; float err_sum; float pad1[30];
  float B[3][kGroups][kEntries];         // rotating accumulator buffers
};

__device__ __forceinline__ uint2 tf2x32(unsigned k0, unsigned k1,
                                        unsigned x0, unsigned x1) {
  unsigned k2 = k0 ^ k1 ^ 0x1BD11BDAu;
  x0 += k0; x1 += k1;
#define TF_RND(r) { x0 += x1; x1 = (x1 << (r)) | (x1 >> (32 - (r))); x1 ^= x0; }
  TF_RND(13) TF_RND(15) TF_RND(26) TF_RND(6)
  x0 += k1; x1 += k2 + 1u;
  TF_RND(17) TF_RND(29) TF_RND(16) TF_RND(24)
  x0 += k2; x1 += k0 + 2u;
  TF_RND(13) TF_RND(15) TF_RND(26) TF_RND(6)
  x0 += k0; x1 += k1 + 3u;
  TF_RND(17) TF_RND(29) TF_RND(16) TF_RND(24)
  x0 += k1; x1 += k2 + 4u;
  TF_RND(13) TF_RND(15) TF_RND(26) TF_RND(6)
  x0 += k2; x1 += k0 + 5u;
#undef TF_RND
  return make_uint2(x0, x1);
}

__device__ __forceinline__ float u01(unsigned b) {
  return __uint_as_float((b >> 9) | 0x3f800000u) - 1.0f;
}

// Two-level monotonic grid barrier: 32 leaves x 16 arrivals, then 32 root
// arrivals. Data safety: the __syncthreads before arrival drains vmcnt (all
// sc1 data ops at L3); the acquire fence after the spin invalidates L1/L2 so
// subsequent normal loads refetch.
__device__ __forceinline__ void gridbar(Ctl* ctl, unsigned& round) {
  ++round;
  __syncthreads();
  if (threadIdx.x == 0) {
    const unsigned leaf = blockIdx.x & 31u;
    unsigned a = __hip_atomic_fetch_add(&ctl->leaf[leaf][0], 1u,
                                        __ATOMIC_RELAXED, AGENT);
    if (a == round * 16u - 1u)   // last of this leaf's 16 blocks this round
      __hip_atomic_fetch_add(&ctl->root, 1u, __ATOMIC_RELAXED, AGENT);
    const unsigned target = round * 32u;
    while (__hip_atomic_load(&ctl->root, __ATOMIC_RELAXED, AGENT) < target)
      __builtin_amdgcn_s_sleep(1);
    __builtin_amdgcn_fence(__ATOMIC_ACQUIRE, "agent");
  }
  __syncthreads();
}

__global__ void init_ctl(unsigned* ws) {
  const unsigned n = (unsigned)(sizeof(Ctl) / 4);
  for (unsigned i = blockIdx.x * blockDim.x + threadIdx.x; i < n;
       i += gridDim.x * blockDim.x)
    ws[i] = 0u;
}

__global__ __launch_bounds__(kThreads, 4) void fsam_nmf(
    const float* __restrict__ eps, const float* __restrict__ w_pre,
    const float* __restrict__ b_pre, const float* __restrict__ w_post1,
    const float* __restrict__ w_post2, float* __restrict__ out, Ctl* ctl) {
  __shared__ __align__(16) float Vs[kC][kPitch];
  __shared__ __align__(16) float Hs[kL][kPitch];
  __shared__ __align__(16) float Pn[3][kL][kPitch];  // q=1..3 H-update partials
  __shared__ __align__(16) float Pv[4][512];         // VH^T tile partials
  __shared__ __align__(16) float Ph[16][64];         // HH^T tile partials
  __shared__ __align__(16) float Ws[kC][kL];
  __shared__ __align__(16) float WtWs[kL * kL];
  __shared__ __align__(16) float hhts[kL * kL];
  __shared__ float reds[8];

  const int tid = threadIdx.x;
  const int t = tid & 127;        // column within block
  const int q = tid >> 7;         // channel quarter 0..3
  const int obase = q * 16;
  const int s = blockIdx.x * kCols + t;   // global spatial column
  unsigned bar_round = 0;

  // ---------------- phase 0: V column = relu(W_pre . eps_col + b) ----------
  // thread (q,t) computes output channels [16q, 16q+16) of column t.
  float acc[16];
#pragma unroll
  for (int o = 0; o < 16; ++o) acc[o] = b_pre[obase + o];
  for (int c = 0; c < kC; ++c) {
    const float e = eps[c * kS + s];
#pragma unroll
    for (int o = 0; o < 16; ++o)
      acc[o] = fmaf(w_pre[(obase + o) * kC + c], e, acc[o]);
  }
  float lsum = 0.0f;
#pragma unroll
  for (int o = 0; o < 16; ++o) {
    acc[o] = fmaxf(acc[o], 0.0f);
    Vs[obase + o][t] = acc[o];
    lsum += acc[o];
  }
  {
    float r = lsum;
#pragma unroll
    for (int off = 32; off > 0; off >>= 1) r += __shfl_down(r, off, 64);
    if ((tid & 63) == 0) reds[tid >> 6] = r;
    __syncthreads();
    if (tid == 0) {
      float sm = 0.0f;
#pragma unroll
      for (int w = 0; w < 8; ++w) sm += reds[w];
      __hip_atomic_fetch_add(&ctl->mean_sum, sm, __ATOMIC_RELAXED, AGENT);
    }
  }
  gridbar(ctl, bar_round);
  const float avg = sqrtf(
      __hip_atomic_load(&ctl->mean_sum, __ATOMIC_RELAXED, AGENT) *
      (1.0f / (4194304.0f * 8.0f)));

  // ---------------- threefry init (JAX-exact) -------------------------------
#if JAX_PARTITIONABLE
  const uint2 kw = tf2x32(0u, 0u, 0u, 0u);
  const uint2 kh = tf2x32(0u, 0u, 0u, 1u);
#else
  const uint2 A0 = tf2x32(0u, 0u, 0u, 2u);
  const uint2 A1 = tf2x32(0u, 0u, 1u, 3u);
  const uint2 kw = make_uint2(A0.x, A1.x);
  const uint2 kh = make_uint2(A0.y, A1.y);
#endif

  if (q == 0) {   // thread (0,t) is the sole owner of column t's H
#if JAX_PARTITIONABLE
#pragma unroll
    for (int l = 0; l < kL; ++l) {
      uint2 r = tf2x32(kh.x, kh.y, 0u, (unsigned)(l * kS + s));
      Hs[l][t] = avg * u01(r.x ^ r.y);
    }
#else
#pragma unroll
    for (int l = 0; l < 4; ++l) {
      unsigned i = (unsigned)(l * kS + s);
      uint2 r = tf2x32(kh.x, kh.y, i, i + 262144u);
      Hs[l][t] = avg * u01(r.x);
      Hs[l + 4][t] = avg * u01(r.y);
    }
#endif
  }
  // W0: 512 flat entries, one per thread
  {
#if JAX_PARTITIONABLE
    uint2 r0 = tf2x32(kw.x, kw.y, 0u, (unsigned)tid);
    (&Ws[0][0])[tid] = avg * u01(r0.x ^ r0.y);
#else
    if (tid < 256) {
      uint2 r = tf2x32(kw.x, kw.y, (unsigned)tid, (unsigned)(tid + 256));
      (&Ws[0][0])[tid] = avg * u01(r.x);
      (&Ws[0][0])[tid + 256] = avg * u01(r.y);
    }
#endif
  }
  __syncthreads();
  if (tid < kL * kL) {
    const int l = tid >> 3, j = tid & 7;
    float sum = 0.0f;
    for (int c = 0; c < kC; ++c) sum = fmaf(Ws[c][l], Ws[c][j], sum);
    WtWs[tid] = sum;
  }
  __syncthreads();

  // ---------------- 50 MU iterations, one grid barrier each -----------------
  for (int it = 0; it < kIters; ++it) {
    // H-update numerator partial over this thread's channel quarter
    float num[kL] = {0, 0, 0, 0, 0, 0, 0, 0};
    for (int ci = 0; ci < 16; ++ci) {
      const int c = obase + ci;
      const float v = Vs[c][t];
      const float4 w0 = *(const float4*)&Ws[c][0];
      const float4 w1 = *(const float4*)&Ws[c][4];
      num[0] = fmaf(v, w0.x, num[0]); num[1] = fmaf(v, w0.y, num[1]);
      num[2] = fmaf(v, w0.z, num[2]); num[3] = fmaf(v, w0.w, num[3]);
      num[4] = fmaf(v, w1.x, num[4]); num[5] = fmaf(v, w1.y, num[5]);
      num[6] = fmaf(v, w1.z, num[6]); num[7] = fmaf(v, w1.w, num[7]);
    }
    if (q != 0) {
#pragma unroll
      for (int l = 0; l < kL; ++l) Pn[q - 1][l][t] = num[l];
    }
    __syncthreads();
    if (q == 0) {
      // sole owner of column t's H: read old, update, write new — no race
      float h[kL], hn[kL];
#pragma unroll
      for (int l = 0; l < kL; ++l) h[l] = Hs[l][t];
#pragma unroll
      for (int l = 0; l < kL; ++l) {
        const float4 a = *(const float4*)&WtWs[l * kL];
        const float4 b = *(const float4*)&WtWs[l * kL + 4];
        float d = kEps;
        d = fmaf(a.x, h[0], d); d = fmaf(a.y, h[1], d);
        d = fmaf(a.z, h[2], d); d = fmaf(a.w, h[3], d);
        d = fmaf(b.x, h[4], d); d = fmaf(b.y, h[5], d);
        d = fmaf(b.z, h[6], d); d = fmaf(b.w, h[7], d);
        const float nm = num[l] + Pn[0][l][t] + Pn[1][l][t] + Pn[2][l][t];
        hn[l] = h[l] * nm / d;
      }
#pragma unroll
      for (int l = 0; l < kL; ++l) Hs[l][t] = hn[l];
    } else if ((blockIdx.x >> 4) == 1) {
      // q!=0 threads idle here: blocks 16..31 zero the it+1 buffer (one group
      // buffer each). 3-buffer rotation keeps {reads (it-1)%3, writes it%3,
      // zero (it+1)%3} distinct between consecutive barriers.
      float* nb = &ctl->B[(it + 1) % 3][blockIdx.x & 15][0];
      for (int k = tid - 128; k < kEntries; k += 384)
        __hip_atomic_store(&nb[k], 0.0f, __ATOMIC_RELAXED, AGENT);
    }
    __syncthreads();

    // VH^T partials: 128 tiles (2c x 2l) x 4 column-ranges of 32
    {
      const int range = tid >> 7;         // 0..3
      const int tile = tid & 127;         // 0..127
      const int c0 = (tile >> 2) * 2;     // 0,2,..62
      const int l0 = (tile & 3) * 2;      // 0,2,4,6
      const int sbeg = range * 32;
      float a00 = 0, a01 = 0, a10 = 0, a11 = 0;
      for (int s4 = sbeg; s4 < sbeg + 32; s4 += 4) {
        const float4 h0 = *(const float4*)&Hs[l0][s4];
        const float4 h1 = *(const float4*)&Hs[l0 + 1][s4];
        const float4 v0 = *(const float4*)&Vs[c0][s4];
        const float4 v1 = *(const float4*)&Vs[c0 + 1][s4];
        a00 = fmaf(v0.x, h0.x, a00); a00 = fmaf(v0.y, h0.y, a00);
        a00 = fmaf(v0.z, h0.z, a00); a00 = fmaf(v0.w, h0.w, a00);
        a01 = fmaf(v0.x, h1.x, a01); a01 = fmaf(v0.y, h1.y, a01);
        a01 = fmaf(v0.z, h1.z, a01); a01 = fmaf(v0.w, h1.w, a01);
        a10 = fmaf(v1.x, h0.x, a10); a10 = fmaf(v1.y, h0.y, a10);
        a10 = fmaf(v1.z, h0.z, a10); a10 = fmaf(v1.w, h0.w, a10);
        a11 = fmaf(v1.x, h1.x, a11); a11 = fmaf(v1.y, h1.y, a11);
        a11 = fmaf(v1.z, h1.z, a11); a11 = fmaf(v1.w, h1.w, a11);
      }
      Pv[range][c0 * 8 + l0] = a00;
      Pv[range][c0 * 8 + l0 + 1] = a01;
      Pv[range][(c0 + 1) * 8 + l0] = a10;
      Pv[range][(c0 + 1) * 8 + l0 + 1] = a11;
    }
    // HH^T partials: 16 tiles (2j x 2l) x 16 column-ranges of 8, threads 0..255
    if (tid < 256) {
      const int tile = tid >> 4, range = tid & 15;
      const int j0 = (tile >> 2) * 2, l0 = (tile & 3) * 2;
      const int sbeg = range * 8;
      float a00 = 0, a01 = 0, a10 = 0, a11 = 0;
      for (int s4 = sbeg; s4 < sbeg + 8; s4 += 4) {
        const float4 x0 = *(const float4*)&Hs[j0][s4];
        const float4 x1 = *(const float4*)&Hs[j0 + 1][s4];
        const float4 y0 = *(const float4*)&Hs[l0][s4];
        const float4 y1 = *(const float4*)&Hs[l0 + 1][s4];
        a00 = fmaf(x0.x, y0.x, a00); a00 = fmaf(x0.y, y0.y, a00);
        a00 = fmaf(x0.z, y0.z, a00); a00 = fmaf(x0.w, y0.w, a00);
        a01 = fmaf(x0.x, y1.x, a01); a01 = fmaf(x0.y, y1.y, a01);
        a01 = fmaf(x0.z, y1.z, a01); a01 = fmaf(x0.w, y1.w, a01);
        a10 = fmaf(x1.x, y0.x, a10); a10 = fmaf(x1.y, y0.y, a10);
        a10 = fmaf(x1.z, y0.z, a10); a10 = fmaf(x1.w, y0.w, a10);
        a11 = fmaf(x1.x, y1.x, a11); a11 = fmaf(x1.y, y1.y, a11);
        a11 = fmaf(x1.z, y1.z, a11); a11 = fmaf(x1.w, y1.w, a11);
      }
      Ph[range][j0 * 8 + l0] = a00;
      Ph[range][j0 * 8 + l0 + 1] = a01;
      Ph[range][(j0 + 1) * 8 + l0] = a10;
      Ph[range][(j0 + 1) * 8 + l0 + 1] = a11;
    }
    __syncthreads();

    // combine partials in LDS, then ONE atomic per entry per block
    float* Bg = &ctl->B[it % 3][blockIdx.x & 15][0];
    {
      const float v = Pv[0][tid] + Pv[1][tid] + Pv[2][tid] + Pv[3][tid];
      __hip_atomic_fetch_add(&Bg[tid], v, __ATOMIC_RELAXED, AGENT);
    }
    if (tid >= 448) {
      const int e = tid - 448;
      float v = 0.0f;
#pragma unroll
      for (int r = 0; r < 16; ++r) v += Ph[r][e];
      __hip_atomic_fetch_add(&Bg[512 + e], v, __ATOMIC_RELAXED, AGENT);
    }

    gridbar(ctl, bar_round);

    // finalize: issue the group-sum global loads FIRST (no sync in the way)
    const float* Bb = &ctl->B[it % 3][0][0];
    float v = 0.0f;
    {
#pragma unroll
      for (int g = 0; g < kGroups; ++g) v += Bb[g * kEntries + tid];
    }
    if (tid < kL * kL) {
      float sum = 0.0f;
#pragma unroll
      for (int g = 0; g < kGroups; ++g) sum += Bb[g * kEntries + 512 + tid];
      hhts[tid] = sum;
    }
    __syncthreads();
    float wn;
    {
      const int c0 = tid >> 3, l0 = tid & 7;
      float d = kEps;
#pragma unroll
      for (int j = 0; j < kL; ++j) d = fmaf(Ws[c0][j], hhts[j * kL + l0], d);
      wn = (&Ws[0][0])[tid] * v / d;
    }
    __syncthreads();
    (&Ws[0][0])[tid] = wn;
    __syncthreads();
    if (tid < kL * kL) {
      const int l = tid >> 3, j = tid & 7;
      float sum = 0.0f;
      for (int c = 0; c < kC; ++c) sum = fmaf(Ws[c][l], Ws[c][j], sum);
      WtWs[tid] = sum;
    }
    __syncthreads();
  }

  // ---------------- epilogue ------------------------------------------------
  float h[kL];
#pragma unroll
  for (int l = 0; l < kL; ++l) h[l] = Hs[l][t];
  // vh for own channel quarter; Frobenius partial; overwrite Vs in place
  float errp = 0.0f;
  for (int ci = 0; ci < 16; ++ci) {
    const int c = obase + ci;
    const float4 w0 = *(const float4*)&Ws[c][0];
    const float4 w1 = *(const float4*)&Ws[c][4];
    float tcc = 0.0f;
    tcc = fmaf(w0.x, h[0], tcc); tcc = fmaf(w0.y, h[1], tcc);
    tcc = fmaf(w0.z, h[2], tcc); tcc = fmaf(w0.w, h[3], tcc);
    tcc = fmaf(w1.x, h[4], tcc); tcc = fmaf(w1.y, h[5], tcc);
    tcc = fmaf(w1.z, h[6], tcc); tcc = fmaf(w1.w, h[7], tcc);
    const float d = Vs[c][t] - tcc;
    errp = fmaf(d, d, errp);
    Vs[c][t] = tcc;               // same thread read+write: no hazard
  }
  {
    float r = errp;
#pragma unroll
    for (int off = 32; off > 0; off >>= 1) r += __shfl_down(r, off, 64);
    __syncthreads();
    if ((tid & 63) == 0) reds[tid >> 6] = r;
    __syncthreads();
    if (tid == 0) {
      float sm = 0.0f;
#pragma unroll
      for (int w = 0; w < 8; ++w) sm += reds[w];
      __hip_atomic_fetch_add(&ctl->err_sum, sm, __ATOMIC_RELAXED, AGENT);
    }
  }
  __syncthreads();   // all vh written before y reads full columns
  // y = relu(W1 . vh): own 16 outputs, full 64-channel input from Vs
  float yacc[16];
#pragma unroll
  for (int o = 0; o < 16; ++o) yacc[o] = 0.0f;
  for (int c = 0; c < kC; ++c) {
    const float vv = Vs[c][t];
#pragma unroll
    for (int o = 0; o < 16; ++o)
      yacc[o] = fmaf(w_post1[(obase + o) * kC + c], vv, yacc[o]);
  }
  __syncthreads();   // all vh reads done before overwrite with y
#pragma unroll
  for (int o = 0; o < 16; ++o) Vs[obase + o][t] = fmaxf(yacc[o], 0.0f);
  __syncthreads();
  // eps_hat = W2 . y: own 16 outputs, full y column from Vs
  float outacc[16];
#pragma unroll
  for (int o = 0; o < 16; ++o) outacc[o] = 0.0f;
  for (int c = 0; c < kC; ++c) {
    const float yv = Vs[c][t];
#pragma unroll
    for (int o = 0; o < 16; ++o)
      outacc[o] = fmaf(w_post2[(obase + o) * kC + c], yv, outacc[o]);
  }
#pragma unroll
  for (int o = 0; o < 16; ++o) out[(obase + o) * kS + s] = outacc[o];

  gridbar(ctl, bar_round);
  if (blockIdx.x == 0 && tid == 0)
    out[kC * kS] = sqrtf(__hip_atomic_load(&ctl->err_sum, __ATOMIC_RELAXED, AGENT));
}

extern "C" void kernel_launch(void* const* d_in, const int* in_sizes, int n_in,
                              void* d_out, int out_size, void* d_ws, size_t ws_size,
                              hipStream_t stream) {
  (void)in_sizes; (void)n_in; (void)out_size; (void)ws_size;
  const float* eps     = (const float*)d_in[0];
  const float* w_pre   = (const float*)d_in[1];
  const float* b_pre   = (const float*)d_in[2];
  const float* w_post1 = (const float*)d_in[3];
  const float* w_post2 = (const float*)d_in[4];
  float* out = (float*)d_out;
  Ctl* ctl = (Ctl*)d_ws;

  init_ctl<<<64, 256, 0, stream>>>((unsigned*)d_ws);
  fsam_nmf<<<kBlocks, kThreads, 0, stream>>>(eps, w_pre, b_pre, w_post1,
                                             w_post2, out, ctl);
}

// Round 5
// 823.930 us; speedup vs baseline: 1.1559x; 1.1559x over previous
//
#include <hip/hip_runtime.h>
#include <stdint.h>

// 1 = JAX >= 0.5 default (jax_threefry_partitionable=True); 0 = legacy scheme.
#define JAX_PARTITIONABLE 1

constexpr int kC = 64;          // channels (= NMF rows T)
constexpr int kS = 65536;       // spatial 16*64*64 (= NMF cols M)
constexpr int kL = 8;           // NMF rank
constexpr int kIters = 50;
constexpr int kBlocks = 256;    // one block per CU: reduction cost ~ blocks
constexpr int kThreads = 1024;  // 16 waves/CU = 4/SIMD for latency hiding
constexpr int kCols = 256;      // columns per block
constexpr int kGroups = 16;     // stage-1 reduction groups (16 blocks/group)
constexpr int kEntries = 576;   // 512 (VH^T) + 64 (HH^T)
constexpr int kPitch = 260;     // LDS row pitch (16B-aligned rows)
constexpr float kEps = 1.1920929e-07f;

#define AGENT __HIP_MEMORY_SCOPE_AGENT

struct Ctl {
  unsigned root;  unsigned pad0[31];     // barrier root counter
  unsigned leaf[16][32];                 // 16 leaf counters, 128 B apart
  float mean_sum; float err_sum; float pad1[30];
  float B[3][kGroups][kEntries];         // rotating accumulator buffers
};

__device__ __forceinline__ uint2 tf2x32(unsigned k0, unsigned k1,
                                        unsigned x0, unsigned x1) {
  unsigned k2 = k0 ^ k1 ^ 0x1BD11BDAu;
  x0 += k0; x1 += k1;
#define TF_RND(r) { x0 += x1; x1 = (x1 << (r)) | (x1 >> (32 - (r))); x1 ^= x0; }
  TF_RND(13) TF_RND(15) TF_RND(26) TF_RND(6)
  x0 += k1; x1 += k2 + 1u;
  TF_RND(17) TF_RND(29) TF_RND(16) TF_RND(24)
  x0 += k2; x1 += k0 + 2u;
  TF_RND(13) TF_RND(15) TF_RND(26) TF_RND(6)
  x0 += k0; x1 += k1 + 3u;
  TF_RND(17) TF_RND(29) TF_RND(16) TF_RND(24)
  x0 += k1; x1 += k2 + 4u;
  TF_RND(13) TF_RND(15) TF_RND(26) TF_RND(6)
  x0 += k2; x1 += k0 + 5u;
#undef TF_RND
  return make_uint2(x0, x1);
}

__device__ __forceinline__ float u01(unsigned b) {
  return __uint_as_float((b >> 9) | 0x3f800000u) - 1.0f;
}

// Two-level monotonic grid barrier: 16 leaves x 16 arrivals, then 16 root
// arrivals. Data safety: the __syncthreads before arrival drains vmcnt (all
// sc1 data ops at L3); the acquire fence after the spin invalidates L1/L2 so
// subsequent normal loads refetch.
__device__ __forceinline__ void gridbar(Ctl* ctl, unsigned& round) {
  ++round;
  __syncthreads();
  if (threadIdx.x == 0) {
    const unsigned leaf = blockIdx.x & 15u;
    unsigned a = __hip_atomic_fetch_add(&ctl->leaf[leaf][0], 1u,
                                        __ATOMIC_RELAXED, AGENT);
    if (a == round * 16u - 1u)   // last of this leaf's 16 blocks this round
      __hip_atomic_fetch_add(&ctl->root, 1u, __ATOMIC_RELAXED, AGENT);
    const unsigned target = round * 16u;
    while (__hip_atomic_load(&ctl->root, __ATOMIC_RELAXED, AGENT) < target)
      __builtin_amdgcn_s_sleep(1);
    __builtin_amdgcn_fence(__ATOMIC_ACQUIRE, "agent");
  }
  __syncthreads();
}

__global__ void init_ctl(unsigned* ws) {
  const unsigned n = (unsigned)(sizeof(Ctl) / 4);
  for (unsigned i = blockIdx.x * blockDim.x + threadIdx.x; i < n;
       i += gridDim.x * blockDim.x)
    ws[i] = 0u;
}

__global__ __launch_bounds__(kThreads, 4) void fsam_nmf(
    const float* __restrict__ eps, const float* __restrict__ w_pre,
    const float* __restrict__ b_pre, const float* __restrict__ w_post1,
    const float* __restrict__ w_post2, float* __restrict__ out, Ctl* ctl) {
  __shared__ __align__(16) float Vs[kC][kPitch];
  __shared__ __align__(16) float Hs[kL][kPitch];
  __shared__ __align__(16) float Pn[3][kL][kPitch];  // q=1..3 H-update partials
  __shared__ __align__(16) float Pv[8][512];         // VH^T tile partials
  __shared__ __align__(16) float Ph[16][64];         // HH^T tile partials
  __shared__ __align__(16) float Ws[kC][kL];
  __shared__ __align__(16) float WtWs[kL * kL];
  __shared__ __align__(16) float hhts[kL * kL];
  __shared__ float reds[16];

  const int tid = threadIdx.x;
  const int t = tid & 255;        // column within block
  const int q = tid >> 8;         // channel quarter 0..3
  const int obase = q * 16;
  const int s = blockIdx.x * kCols + t;   // global spatial column
  unsigned bar_round = 0;

  // ---------------- phase 0: V column = relu(W_pre . eps_col + b) ----------
  // thread (q,t) computes channels [16q,16q+16) of column t; V is constant
  // over all 50 iterations, so keep this thread's 16 values in registers.
  float vreg[16];
#pragma unroll
  for (int o = 0; o < 16; ++o) vreg[o] = b_pre[obase + o];
  for (int c = 0; c < kC; ++c) {
    const float e = eps[c * kS + s];
#pragma unroll
    for (int o = 0; o < 16; ++o)
      vreg[o] = fmaf(w_pre[(obase + o) * kC + c], e, vreg[o]);
  }
  float lsum = 0.0f;
#pragma unroll
  for (int o = 0; o < 16; ++o) {
    vreg[o] = fmaxf(vreg[o], 0.0f);
    Vs[obase + o][t] = vreg[o];
    lsum += vreg[o];
  }
  {
    float r = lsum;
#pragma unroll
    for (int off = 32; off > 0; off >>= 1) r += __shfl_down(r, off, 64);
    if ((tid & 63) == 0) reds[tid >> 6] = r;
    __syncthreads();
    if (tid == 0) {
      float sm = 0.0f;
#pragma unroll
      for (int w = 0; w < 16; ++w) sm += reds[w];
      __hip_atomic_fetch_add(&ctl->mean_sum, sm, __ATOMIC_RELAXED, AGENT);
    }
  }
  gridbar(ctl, bar_round);
  const float avg = sqrtf(
      __hip_atomic_load(&ctl->mean_sum, __ATOMIC_RELAXED, AGENT) *
      (1.0f / (4194304.0f * 8.0f)));

  // ---------------- threefry init (JAX-exact) -------------------------------
#if JAX_PARTITIONABLE
  const uint2 kw = tf2x32(0u, 0u, 0u, 0u);
  const uint2 kh = tf2x32(0u, 0u, 0u, 1u);
#else
  const uint2 A0 = tf2x32(0u, 0u, 0u, 2u);
  const uint2 A1 = tf2x32(0u, 0u, 1u, 3u);
  const uint2 kw = make_uint2(A0.x, A1.x);
  const uint2 kh = make_uint2(A0.y, A1.y);
#endif

  if (q == 0) {   // thread (0,t) is the sole owner of column t's H
#if JAX_PARTITIONABLE
#pragma unroll
    for (int l = 0; l < kL; ++l) {
      uint2 r = tf2x32(kh.x, kh.y, 0u, (unsigned)(l * kS + s));
      Hs[l][t] = avg * u01(r.x ^ r.y);
    }
#else
#pragma unroll
    for (int l = 0; l < 4; ++l) {
      unsigned i = (unsigned)(l * kS + s);
      uint2 r = tf2x32(kh.x, kh.y, i, i + 262144u);
      Hs[l][t] = avg * u01(r.x);
      Hs[l + 4][t] = avg * u01(r.y);
    }
#endif
  }
  // W0: 512 flat entries
  if (tid < 512) {
#if JAX_PARTITIONABLE
    uint2 r0 = tf2x32(kw.x, kw.y, 0u, (unsigned)tid);
    (&Ws[0][0])[tid] = avg * u01(r0.x ^ r0.y);
#else
    if (tid < 256) {
      uint2 r = tf2x32(kw.x, kw.y, (unsigned)tid, (unsigned)(tid + 256));
      (&Ws[0][0])[tid] = avg * u01(r.x);
      (&Ws[0][0])[tid + 256] = avg * u01(r.y);
    }
#endif
  }
  __syncthreads();
  if (tid < kL * kL) {
    const int l = tid >> 3, j = tid & 7;
    float sum = 0.0f;
    for (int c = 0; c < kC; ++c) sum = fmaf(Ws[c][l], Ws[c][j], sum);
    WtWs[tid] = sum;
  }
  __syncthreads();

  // ---------------- 50 MU iterations, one grid barrier each -----------------
  for (int it = 0; it < kIters; ++it) {
    // H-update numerator partial over this thread's channel quarter (V in regs)
    float num[kL] = {0, 0, 0, 0, 0, 0, 0, 0};
#pragma unroll
    for (int ci = 0; ci < 16; ++ci) {
      const int c = obase + ci;
      const float v = vreg[ci];
      const float4 w0 = *(const float4*)&Ws[c][0];
      const float4 w1 = *(const float4*)&Ws[c][4];
      num[0] = fmaf(v, w0.x, num[0]); num[1] = fmaf(v, w0.y, num[1]);
      num[2] = fmaf(v, w0.z, num[2]); num[3] = fmaf(v, w0.w, num[3]);
      num[4] = fmaf(v, w1.x, num[4]); num[5] = fmaf(v, w1.y, num[5]);
      num[6] = fmaf(v, w1.z, num[6]); num[7] = fmaf(v, w1.w, num[7]);
    }
    if (q != 0) {
#pragma unroll
      for (int l = 0; l < kL; ++l) Pn[q - 1][l][t] = num[l];
    }
    __syncthreads();
    if (q == 0) {
      // sole owner of column t's H: read old, update, write new — no race
      float h[kL], hn[kL];
#pragma unroll
      for (int l = 0; l < kL; ++l) h[l] = Hs[l][t];
#pragma unroll
      for (int l = 0; l < kL; ++l) {
        const float4 a = *(const float4*)&WtWs[l * kL];
        const float4 b = *(const float4*)&WtWs[l * kL + 4];
        float d = kEps;
        d = fmaf(a.x, h[0], d); d = fmaf(a.y, h[1], d);
        d = fmaf(a.z, h[2], d); d = fmaf(a.w, h[3], d);
        d = fmaf(b.x, h[4], d); d = fmaf(b.y, h[5], d);
        d = fmaf(b.z, h[6], d); d = fmaf(b.w, h[7], d);
        const float nm = num[l] + Pn[0][l][t] + Pn[1][l][t] + Pn[2][l][t];
        hn[l] = h[l] * nm / d;
      }
#pragma unroll
      for (int l = 0; l < kL; ++l) Hs[l][t] = hn[l];
    } else if ((blockIdx.x >> 4) == 1) {
      // q!=0 threads idle here: blocks 16..31 zero the it+1 buffer (one group
      // buffer each). 3-buffer rotation keeps {reads (it-1)%3, writes it%3,
      // zero (it+1)%3} distinct between consecutive barriers.
      float* nb = &ctl->B[(it + 1) % 3][blockIdx.x & 15][0];
      for (int k = tid - 256; k < kEntries; k += 768)
        __hip_atomic_store(&nb[k], 0.0f, __ATOMIC_RELAXED, AGENT);
    }
    __syncthreads();

    // VH^T partials: 128 tiles x 8 column-ranges of 32. Tiles pair rows
    // (c0, c0+32): bank-start c0*4 over c0=0..15 -> 8 starts x2 = 2-way
    // conflict (free) instead of the 4-way from (2c,2c+1) pairing.
    {
      const int range = tid >> 7;         // 0..7
      const int tile = tid & 127;         // 0..127
      const int c0 = tile >> 2;           // 0..31
      const int l0 = (tile & 3) * 2;      // 0,2,4,6
      const int sbeg = range * 32;
      float a00 = 0, a01 = 0, a10 = 0, a11 = 0;
      for (int s4 = sbeg; s4 < sbeg + 32; s4 += 4) {
        const float4 h0 = *(const float4*)&Hs[l0][s4];
        const float4 h1 = *(const float4*)&Hs[l0 + 1][s4];
        const float4 v0 = *(const float4*)&Vs[c0][s4];
        const float4 v1 = *(const float4*)&Vs[c0 + 32][s4];
        a00 = fmaf(v0.x, h0.x, a00); a00 = fmaf(v0.y, h0.y, a00);
        a00 = fmaf(v0.z, h0.z, a00); a00 = fmaf(v0.w, h0.w, a00);
        a01 = fmaf(v0.x, h1.x, a01); a01 = fmaf(v0.y, h1.y, a01);
        a01 = fmaf(v0.z, h1.z, a01); a01 = fmaf(v0.w, h1.w, a01);
        a10 = fmaf(v1.x, h0.x, a10); a10 = fmaf(v1.y, h0.y, a10);
        a10 = fmaf(v1.z, h0.z, a10); a10 = fmaf(v1.w, h0.w, a10);
        a11 = fmaf(v1.x, h1.x, a11); a11 = fmaf(v1.y, h1.y, a11);
        a11 = fmaf(v1.z, h1.z, a11); a11 = fmaf(v1.w, h1.w, a11);
      }
      Pv[range][c0 * 8 + l0] = a00;
      Pv[range][c0 * 8 + l0 + 1] = a01;
      Pv[range][(c0 + 32) * 8 + l0] = a10;
      Pv[range][(c0 + 32) * 8 + l0 + 1] = a11;
    }
    // HH^T partials: 16 tiles (2j x 2l) x 16 column-ranges of 16, threads 0..255
    if (tid < 256) {
      const int tile = tid >> 4, range = tid & 15;
      const int j0 = (tile >> 2) * 2, l0 = (tile & 3) * 2;
      const int sbeg = range * 16;
      float a00 = 0, a01 = 0, a10 = 0, a11 = 0;
      for (int s4 = sbeg; s4 < sbeg + 16; s4 += 4) {
        const float4 x0 = *(const float4*)&Hs[j0][s4];
        const float4 x1 = *(const float4*)&Hs[j0 + 1][s4];
        const float4 y0 = *(const float4*)&Hs[l0][s4];
        const float4 y1 = *(const float4*)&Hs[l0 + 1][s4];
        a00 = fmaf(x0.x, y0.x, a00); a00 = fmaf(x0.y, y0.y, a00);
        a00 = fmaf(x0.z, y0.z, a00); a00 = fmaf(x0.w, y0.w, a00);
        a01 = fmaf(x0.x, y1.x, a01); a01 = fmaf(x0.y, y1.y, a01);
        a01 = fmaf(x0.z, y1.z, a01); a01 = fmaf(x0.w, y1.w, a01);
        a10 = fmaf(x1.x, y0.x, a10); a10 = fmaf(x1.y, y0.y, a10);
        a10 = fmaf(x1.z, y0.z, a10); a10 = fmaf(x1.w, y0.w, a10);
        a11 = fmaf(x1.x, y1.x, a11); a11 = fmaf(x1.y, y1.y, a11);
        a11 = fmaf(x1.z, y1.z, a11); a11 = fmaf(x1.w, y1.w, a11);
      }
      Ph[range][j0 * 8 + l0] = a00;
      Ph[range][j0 * 8 + l0 + 1] = a01;
      Ph[range][(j0 + 1) * 8 + l0] = a10;
      Ph[range][(j0 + 1) * 8 + l0 + 1] = a11;
    }
    __syncthreads();

    // combine partials in LDS, then ONE atomic per entry per block
    float* Bg = &ctl->B[it % 3][blockIdx.x & 15][0];
    if (tid < 512) {
      float v = 0.0f;
#pragma unroll
      for (int r = 0; r < 8; ++r) v += Pv[r][tid];
      __hip_atomic_fetch_add(&Bg[tid], v, __ATOMIC_RELAXED, AGENT);
    } else if (tid < 576) {
      const int e = tid - 512;
      float v = 0.0f;
#pragma unroll
      for (int r = 0; r < 16; ++r) v += Ph[r][e];
      __hip_atomic_fetch_add(&Bg[512 + e], v, __ATOMIC_RELAXED, AGENT);
    }

    gridbar(ctl, bar_round);

    // finalize: issue the group-sum global loads FIRST (no sync in the way)
    const float* Bb = &ctl->B[it % 3][0][0];
    float v = 0.0f;
    if (tid < 512) {
#pragma unroll
      for (int g = 0; g < kGroups; ++g) v += Bb[g * kEntries + tid];
    }
    if (tid < kL * kL) {
      float sum = 0.0f;
#pragma unroll
      for (int g = 0; g < kGroups; ++g) sum += Bb[g * kEntries + 512 + tid];
      hhts[tid] = sum;
    }
    __syncthreads();
    float wn = 0.0f;
    if (tid < 512) {
      const int c0 = tid >> 3, l0 = tid & 7;
      float d = kEps;
#pragma unroll
      for (int j = 0; j < kL; ++j) d = fmaf(Ws[c0][j], hhts[j * kL + l0], d);
      wn = (&Ws[0][0])[tid] * v / d;
    }
    __syncthreads();
    if (tid < 512) (&Ws[0][0])[tid] = wn;
    __syncthreads();
    if (tid < kL * kL) {
      const int l = tid >> 3, j = tid & 7;
      float sum = 0.0f;
      for (int c = 0; c < kC; ++c) sum = fmaf(Ws[c][l], Ws[c][j], sum);
      WtWs[tid] = sum;
    }
    __syncthreads();
  }

  // ---------------- epilogue ------------------------------------------------
  float h[kL];
#pragma unroll
  for (int l = 0; l < kL; ++l) h[l] = Hs[l][t];
  // vh for own channel quarter; Frobenius partial vs register V; write Vs=vh
  float errp = 0.0f;
#pragma unroll
  for (int ci = 0; ci < 16; ++ci) {
    const int c = obase + ci;
    const float4 w0 = *(const float4*)&Ws[c][0];
    const float4 w1 = *(const float4*)&Ws[c][4];
    float tcc = 0.0f;
    tcc = fmaf(w0.x, h[0], tcc); tcc = fmaf(w0.y, h[1], tcc);
    tcc = fmaf(w0.z, h[2], tcc); tcc = fmaf(w0.w, h[3], tcc);
    tcc = fmaf(w1.x, h[4], tcc); tcc = fmaf(w1.y, h[5], tcc);
    tcc = fmaf(w1.z, h[6], tcc); tcc = fmaf(w1.w, h[7], tcc);
    const float d = vreg[ci] - tcc;
    errp = fmaf(d, d, errp);
    Vs[c][t] = tcc;
  }
  {
    float r = errp;
#pragma unroll
    for (int off = 32; off > 0; off >>= 1) r += __shfl_down(r, off, 64);
    __syncthreads();
    if ((tid & 63) == 0) reds[tid >> 6] = r;
    __syncthreads();
    if (tid == 0) {
      float sm = 0.0f;
#pragma unroll
      for (int w = 0; w < 16; ++w) sm += reds[w];
      __hip_atomic_fetch_add(&ctl->err_sum, sm, __ATOMIC_RELAXED, AGENT);
    }
  }
  __syncthreads();   // all vh written before y reads full columns
  // y = relu(W1 . vh): own 16 outputs, full 64-channel input from Vs
  float yacc[16];
#pragma unroll
  for (int o = 0; o < 16; ++o) yacc[o] = 0.0f;
  for (int c = 0; c < kC; ++c) {
    const float vv = Vs[c][t];
#pragma unroll
    for (int o = 0; o < 16; ++o)
      yacc[o] = fmaf(w_post1[(obase + o) * kC + c], vv, yacc[o]);
  }
  __syncthreads();   // all vh reads done before overwrite with y
#pragma unroll
  for (int o = 0; o < 16; ++o) Vs[obase + o][t] = fmaxf(yacc[o], 0.0f);
  __syncthreads();
  // eps_hat = W2 . y: own 16 outputs, full y column from Vs
  float outacc[16];
#pragma unroll
  for (int o = 0; o < 16; ++o) outacc[o] = 0.0f;
  for (int c = 0; c < kC; ++c) {
    const float yv = Vs[c][t];
#pragma unroll
    for (int o = 0; o < 16; ++o)
      outacc[o] = fmaf(w_post2[(obase + o) * kC + c], yv, outacc[o]);
  }
#pragma unroll
  for (int o = 0; o < 16; ++o) out[(obase + o) * kS + s] = outacc[o];

  gridbar(ctl, bar_round);
  if (blockIdx.x == 0 && tid == 0)
    out[kC * kS] = sqrtf(__hip_atomic_load(&ctl->err_sum, __ATOMIC_RELAXED, AGENT));
}

extern "C" void kernel_launch(void* const* d_in, const int* in_sizes, int n_in,
                              void* d_out, int out_size, void* d_ws, size_t ws_size,
                              hipStream_t stream) {
  (void)in_sizes; (void)n_in; (void)out_size; (void)ws_size;
  const float* eps     = (const float*)d_in[0];
  const float* w_pre   = (const float*)d_in[1];
  const float* b_pre   = (const float*)d_in[2];
  const float* w_post1 = (const float*)d_in[3];
  const float* w_post2 = (const float*)d_in[4];
  float* out = (float*)d_out;
  Ctl* ctl = (Ctl*)d_ws;

  init_ctl<<<64, 256, 0, stream>>>((unsigned*)d_ws);
  fsam_nmf<<<kBlocks, kThreads, 0, stream>>>(eps, w_pre, b_pre, w_post1,
                                             w_post2, out, ctl);
}

// Round 6
// 646.996 us; speedup vs baseline: 1.4720x; 1.2735x over previous
//
#include <hip/hip_runtime.h>
#include <stdint.h>

// 1 = JAX >= 0.5 default (jax_threefry_partitionable=True); 0 = legacy scheme.
#define JAX_PARTITIONABLE 1

constexpr int kC = 64;          // channels (= NMF rows T)
constexpr int kS = 65536;       // spatial 16*64*64 (= NMF cols M)
constexpr int kL = 8;           // NMF rank
constexpr int kIters = 50;
constexpr int kBlocks = 256;    // one block per CU (R4 showed blocks scale sync cost)
constexpr int kThreads = 512;   // R5 showed 1024 thr adds sync-convoy cost
constexpr int kCols = 256;      // columns per block
constexpr int kGroups = 4;      // reduction groups (64 blocks/group)
constexpr int kEntries = 576;   // 512 (VH^T) + 64 (HH^T)
constexpr int kHP = 260;        // Hs pitch
constexpr int kVP = 68;         // Vt pitch (V stored TRANSPOSED: [col][ch])
constexpr int kNP = 258;        // Pn pitch (even for float2 writes)
constexpr float kEps = 1.1920929e-07f;

#define AGENT __HIP_MEMORY_SCOPE_AGENT

struct Ctl {
  unsigned root;  unsigned pad0[31];
  unsigned leaf[16][32];                 // 16 leaf counters, 128 B apart
  float mean_sum; float err_sum; float pad1[30];
  float B[3][kGroups][kEntries];         // rotating accumulator buffers
};

__device__ __forceinline__ uint2 tf2x32(unsigned k0, unsigned k1,
                                        unsigned x0, unsigned x1) {
  unsigned k2 = k0 ^ k1 ^ 0x1BD11BDAu;
  x0 += k0; x1 += k1;
#define TF_RND(r) { x0 += x1; x1 = (x1 << (r)) | (x1 >> (32 - (r))); x1 ^= x0; }
  TF_RND(13) TF_RND(15) TF_RND(26) TF_RND(6)
  x0 += k1; x1 += k2 + 1u;
  TF_RND(17) TF_RND(29) TF_RND(16) TF_RND(24)
  x0 += k2; x1 += k0 + 2u;
  TF_RND(13) TF_RND(15) TF_RND(26) TF_RND(6)
  x0 += k0; x1 += k1 + 3u;
  TF_RND(17) TF_RND(29) TF_RND(16) TF_RND(24)
  x0 += k1; x1 += k2 + 4u;
  TF_RND(13) TF_RND(15) TF_RND(26) TF_RND(6)
  x0 += k2; x1 += k0 + 5u;
#undef TF_RND
  return make_uint2(x0, x1);
}

__device__ __forceinline__ float u01(unsigned b) {
  return __uint_as_float((b >> 9) | 0x3f800000u) - 1.0f;
}

// Two-level monotonic grid barrier (16 leaves x 16 arrivals -> 16 root).
__device__ __forceinline__ void gridbar(Ctl* ctl, unsigned& round) {
  ++round;
  __syncthreads();
  if (threadIdx.x == 0) {
    const unsigned leaf = blockIdx.x & 15u;
    unsigned a = __hip_atomic_fetch_add(&ctl->leaf[leaf][0], 1u,
                                        __ATOMIC_RELAXED, AGENT);
    if (a == round * 16u - 1u)
      __hip_atomic_fetch_add(&ctl->root, 1u, __ATOMIC_RELAXED, AGENT);
    const unsigned target = round * 16u;
    while (__hip_atomic_load(&ctl->root, __ATOMIC_RELAXED, AGENT) < target)
      __builtin_amdgcn_s_sleep(1);
    __builtin_amdgcn_fence(__ATOMIC_ACQUIRE, "agent");
  }
  __syncthreads();
}

__global__ void init_ctl(unsigned* ws) {
  const unsigned n = (unsigned)(sizeof(Ctl) / 4);
  for (unsigned i = blockIdx.x * blockDim.x + threadIdx.x; i < n;
       i += gridDim.x * blockDim.x)
    ws[i] = 0u;
}

__global__ __launch_bounds__(kThreads, 2) void fsam_nmf(
    const float* __restrict__ eps, const float* __restrict__ w_pre,
    const float* __restrict__ b_pre, const float* __restrict__ w_post1,
    const float* __restrict__ w_post2, float* __restrict__ out, Ctl* ctl) {
  __shared__ __align__(16) float Vt[kCols][kVP];    // V^T (then vhat, then y)
  __shared__ __align__(16) float Hs[kL][kHP];
  __shared__ __align__(16) float Pn[4][kL][kNP];    // phase-1 num partials
  __shared__ __align__(16) float Pv[8][512];        // VH^T range partials
  __shared__ __align__(16) float Ph[16][64];        // HH^T range partials
  __shared__ __align__(16) float Pw[8][64];         // W^T W chunk partials
  __shared__ __align__(16) float Ws[kC][kL];
  __shared__ __align__(16) float WtWs[64];
  __shared__ __align__(16) float hhts[64];
  __shared__ float reds[8];

  const int tid = threadIdx.x;
  const int g = tid >> 7;                 // channel 16-group (0..3)
  const int p = tid & 127;                // col-pair (cols 2p, 2p+1)
  const int obase = g * 16;
  const int sb = blockIdx.x * kCols;      // block's first global column
  unsigned bar_round = 0;

  // ------------- phase 0: V cols = relu(W_pre . eps + b), col-pair ---------
  float vreg[2][16];
#pragma unroll
  for (int o = 0; o < 16; ++o) { vreg[0][o] = b_pre[obase + o]; vreg[1][o] = vreg[0][o]; }
  for (int c = 0; c < kC; ++c) {
    const float2 e2 = *(const float2*)(eps + (size_t)c * kS + sb + 2 * p);
#pragma unroll
    for (int o = 0; o < 16; ++o) {
      const float w = w_pre[(obase + o) * kC + c];
      vreg[0][o] = fmaf(w, e2.x, vreg[0][o]);
      vreg[1][o] = fmaf(w, e2.y, vreg[1][o]);
    }
  }
  float lsum = 0.0f;
#pragma unroll
  for (int col = 0; col < 2; ++col) {
#pragma unroll
    for (int o = 0; o < 16; ++o) {
      vreg[col][o] = fmaxf(vreg[col][o], 0.0f);
      lsum += vreg[col][o];
    }
#pragma unroll
    for (int k = 0; k < 4; ++k)
      *(float4*)&Vt[2 * p + col][obase + 4 * k] =
          make_float4(vreg[col][4 * k], vreg[col][4 * k + 1],
                      vreg[col][4 * k + 2], vreg[col][4 * k + 3]);
  }
  {
    float r = lsum;
#pragma unroll
    for (int off = 32; off > 0; off >>= 1) r += __shfl_down(r, off, 64);
    if ((tid & 63) == 0) reds[tid >> 6] = r;
    __syncthreads();
    if (tid == 0) {
      float sm = 0.0f;
#pragma unroll
      for (int w = 0; w < 8; ++w) sm += reds[w];
      __hip_atomic_fetch_add(&ctl->mean_sum, sm, __ATOMIC_RELAXED, AGENT);
    }
  }
  gridbar(ctl, bar_round);
  const float avg = sqrtf(
      __hip_atomic_load(&ctl->mean_sum, __ATOMIC_RELAXED, AGENT) *
      (1.0f / (4194304.0f * 8.0f)));

  // ------------- threefry init (JAX-exact) ---------------------------------
#if JAX_PARTITIONABLE
  const uint2 kw = tf2x32(0u, 0u, 0u, 0u);
  const uint2 kh = tf2x32(0u, 0u, 0u, 1u);
#else
  const uint2 A0 = tf2x32(0u, 0u, 0u, 2u);
  const uint2 A1 = tf2x32(0u, 0u, 1u, 3u);
  const uint2 kw = make_uint2(A0.x, A1.x);
  const uint2 kh = make_uint2(A0.y, A1.y);
#endif
  if (tid < 256) {   // thread tid inits column tid's H
    const int s = sb + tid;
#if JAX_PARTITIONABLE
#pragma unroll
    for (int l = 0; l < kL; ++l) {
      uint2 r = tf2x32(kh.x, kh.y, 0u, (unsigned)(l * kS + s));
      Hs[l][tid] = avg * u01(r.x ^ r.y);
    }
#else
#pragma unroll
    for (int l = 0; l < 4; ++l) {
      unsigned i = (unsigned)(l * kS + s);
      uint2 r = tf2x32(kh.x, kh.y, i, i + 262144u);
      Hs[l][tid] = avg * u01(r.x);
      Hs[l + 4][tid] = avg * u01(r.y);
    }
#endif
  }
  {
#if JAX_PARTITIONABLE
    uint2 r0 = tf2x32(kw.x, kw.y, 0u, (unsigned)tid);
    (&Ws[0][0])[tid] = avg * u01(r0.x ^ r0.y);
#else
    if (tid < 256) {
      uint2 r = tf2x32(kw.x, kw.y, (unsigned)tid, (unsigned)(tid + 256));
      (&Ws[0][0])[tid] = avg * u01(r.x);
      (&Ws[0][0])[tid + 256] = avg * u01(r.y);
    }
#endif
  }
  __syncthreads();

  // ------------- 50 MU iterations ------------------------------------------
  for (int it = 0; it < kIters; ++it) {
    // === region A: W^T W chunk partials + phase-1 numerator (reads Ws) ====
    {
      const int e = tid & 63, chunk = tid >> 6, cb = chunk * 8;
      const int l = e >> 3, j = e & 7;
      float s = 0.0f;
#pragma unroll
      for (int cc = 0; cc < 8; ++cc)
        s = fmaf(Ws[cb + cc][l], Ws[cb + cc][j], s);
      Pw[chunk][e] = s;
    }
    {
      float num[2][kL] = {};
#pragma unroll
      for (int ci = 0; ci < 16; ++ci) {
        const int c = obase + ci;
        const float4 w0 = *(const float4*)&Ws[c][0];
        const float4 w1 = *(const float4*)&Ws[c][4];
        const float v0 = vreg[0][ci], v1 = vreg[1][ci];
        num[0][0] = fmaf(v0, w0.x, num[0][0]); num[0][1] = fmaf(v0, w0.y, num[0][1]);
        num[0][2] = fmaf(v0, w0.z, num[0][2]); num[0][3] = fmaf(v0, w0.w, num[0][3]);
        num[0][4] = fmaf(v0, w1.x, num[0][4]); num[0][5] = fmaf(v0, w1.y, num[0][5]);
        num[0][6] = fmaf(v0, w1.z, num[0][6]); num[0][7] = fmaf(v0, w1.w, num[0][7]);
        num[1][0] = fmaf(v1, w0.x, num[1][0]); num[1][1] = fmaf(v1, w0.y, num[1][1]);
        num[1][2] = fmaf(v1, w0.z, num[1][2]); num[1][3] = fmaf(v1, w0.w, num[1][3]);
        num[1][4] = fmaf(v1, w1.x, num[1][4]); num[1][5] = fmaf(v1, w1.y, num[1][5]);
        num[1][6] = fmaf(v1, w1.z, num[1][6]); num[1][7] = fmaf(v1, w1.w, num[1][7]);
      }
#pragma unroll
      for (int l = 0; l < kL; ++l)
        *(float2*)&Pn[g][l][2 * p] = make_float2(num[0][l], num[1][l]);
    }
    __syncthreads();                                   // s1
    // === region B: finish WtW; read h + num sums ==========================
    const int col = tid & 255, lh = tid >> 8;
    float h[kL], nm[4];
#pragma unroll
    for (int l = 0; l < kL; ++l) h[l] = Hs[l][col];
#pragma unroll
    for (int k = 0; k < 4; ++k) {
      const int l = lh * 4 + k;
      nm[k] = Pn[0][l][col] + Pn[1][l][col] + Pn[2][l][col] + Pn[3][l][col];
    }
    if (tid < 64) {
      float s = 0.0f;
#pragma unroll
      for (int r = 0; r < 8; ++r) s += Pw[r][tid];
      WtWs[tid] = s;
    }
    __syncthreads();                                   // s2
    // === region C: H update (thread = col x l-half) =======================
#pragma unroll
    for (int k = 0; k < 4; ++k) {
      const int l = lh * 4 + k;
      const float4 a = *(const float4*)&WtWs[l * kL];
      const float4 b = *(const float4*)&WtWs[l * kL + 4];
      float d = kEps;
      d = fmaf(a.x, h[0], d); d = fmaf(a.y, h[1], d);
      d = fmaf(a.z, h[2], d); d = fmaf(a.w, h[3], d);
      d = fmaf(b.x, h[4], d); d = fmaf(b.y, h[5], d);
      d = fmaf(b.z, h[6], d); d = fmaf(b.w, h[7], d);
      Hs[l][col] = h[l] * nm[k] / d;
    }
    __syncthreads();                                   // s3
    // === region D: HH^T (tid<256) + VH^T (all, transposed V) ==============
    if (tid < 256) {
      const int tle = tid & 15, rng = tid >> 4;
      const int j0 = (tle >> 2) * 2, l0 = (tle & 3) * 2;
      const int s0 = rng * 16;
      float a00 = 0, a01 = 0, a10 = 0, a11 = 0;
      for (int s4 = s0; s4 < s0 + 16; s4 += 4) {
        const float4 x0 = *(const float4*)&Hs[j0][s4];
        const float4 x1 = *(const float4*)&Hs[j0 + 1][s4];
        const float4 y0 = *(const float4*)&Hs[l0][s4];
        const float4 y1 = *(const float4*)&Hs[l0 + 1][s4];
        a00 = fmaf(x0.x, y0.x, a00); a00 = fmaf(x0.y, y0.y, a00);
        a00 = fmaf(x0.z, y0.z, a00); a00 = fmaf(x0.w, y0.w, a00);
        a01 = fmaf(x0.x, y1.x, a01); a01 = fmaf(x0.y, y1.y, a01);
        a01 = fmaf(x0.z, y1.z, a01); a01 = fmaf(x0.w, y1.w, a01);
        a10 = fmaf(x1.x, y0.x, a10); a10 = fmaf(x1.y, y0.y, a10);
        a10 = fmaf(x1.z, y0.z, a10); a10 = fmaf(x1.w, y0.w, a10);
        a11 = fmaf(x1.x, y1.x, a11); a11 = fmaf(x1.y, y1.y, a11);
        a11 = fmaf(x1.z, y1.z, a11); a11 = fmaf(x1.w, y1.w, a11);
      }
      Ph[rng][j0 * 8 + l0] = a00;
      Ph[rng][j0 * 8 + l0 + 1] = a01;
      Ph[rng][(j0 + 1) * 8 + l0] = a10;
      Ph[rng][(j0 + 1) * 8 + l0 + 1] = a11;
    }
    {
      // 64 tiles (16 c-quads x 4 l-pairs) x 8 ranges of 32 cols.
      const int tile = tid & 63, rng = tid >> 6;
      const int cq = tile & 15, lp = tile >> 4;
      const int cb = cq * 4, lb = lp * 2;
      float acc[4][2] = {};
      for (int s4 = rng * 32; s4 < rng * 32 + 32; s4 += 4) {
        const float4 h0 = *(const float4*)&Hs[lb][s4];
        const float4 h1 = *(const float4*)&Hs[lb + 1][s4];
        const float4 va = *(const float4*)&Vt[s4][cb];
        const float4 vb = *(const float4*)&Vt[s4 + 1][cb];
        const float4 vc = *(const float4*)&Vt[s4 + 2][cb];
        const float4 vd = *(const float4*)&Vt[s4 + 3][cb];
        acc[0][0] = fmaf(va.x, h0.x, acc[0][0]); acc[0][1] = fmaf(va.x, h1.x, acc[0][1]);
        acc[1][0] = fmaf(va.y, h0.x, acc[1][0]); acc[1][1] = fmaf(va.y, h1.x, acc[1][1]);
        acc[2][0] = fmaf(va.z, h0.x, acc[2][0]); acc[2][1] = fmaf(va.z, h1.x, acc[2][1]);
        acc[3][0] = fmaf(va.w, h0.x, acc[3][0]); acc[3][1] = fmaf(va.w, h1.x, acc[3][1]);
        acc[0][0] = fmaf(vb.x, h0.y, acc[0][0]); acc[0][1] = fmaf(vb.x, h1.y, acc[0][1]);
        acc[1][0] = fmaf(vb.y, h0.y, acc[1][0]); acc[1][1] = fmaf(vb.y, h1.y, acc[1][1]);
        acc[2][0] = fmaf(vb.z, h0.y, acc[2][0]); acc[2][1] = fmaf(vb.z, h1.y, acc[2][1]);
        acc[3][0] = fmaf(vb.w, h0.y, acc[3][0]); acc[3][1] = fmaf(vb.w, h1.y, acc[3][1]);
        acc[0][0] = fmaf(vc.x, h0.z, acc[0][0]); acc[0][1] = fmaf(vc.x, h1.z, acc[0][1]);
        acc[1][0] = fmaf(vc.y, h0.z, acc[1][0]); acc[1][1] = fmaf(vc.y, h1.z, acc[1][1]);
        acc[2][0] = fmaf(vc.z, h0.z, acc[2][0]); acc[2][1] = fmaf(vc.z, h1.z, acc[2][1]);
        acc[3][0] = fmaf(vc.w, h0.z, acc[3][0]); acc[3][1] = fmaf(vc.w, h1.z, acc[3][1]);
        acc[0][0] = fmaf(vd.x, h0.w, acc[0][0]); acc[0][1] = fmaf(vd.x, h1.w, acc[0][1]);
        acc[1][0] = fmaf(vd.y, h0.w, acc[1][0]); acc[1][1] = fmaf(vd.y, h1.w, acc[1][1]);
        acc[2][0] = fmaf(vd.z, h0.w, acc[2][0]); acc[2][1] = fmaf(vd.z, h1.w, acc[2][1]);
        acc[3][0] = fmaf(vd.w, h0.w, acc[3][0]); acc[3][1] = fmaf(vd.w, h1.w, acc[3][1]);
      }
#pragma unroll
      for (int j = 0; j < 4; ++j)
        *(float2*)&Pv[rng][cq * 32 + lp * 8 + j * 2] =
            make_float2(acc[j][0], acc[j][1]);
    }
    __syncthreads();                                   // s4
    // === region E: combine + global atomics; zero next buffer =============
    float* Bg = &ctl->B[it % 3][blockIdx.x & 3][0];
    {
      const int c = tid >> 3, l = tid & 7;
      const int slot = (c >> 2) * 32 + (l >> 1) * 8 + (c & 3) * 2 + (l & 1);
      float v = 0.0f;
#pragma unroll
      for (int r = 0; r < 8; ++r) v += Pv[r][slot];
      __hip_atomic_fetch_add(&Bg[tid], v, __ATOMIC_RELAXED, AGENT);
    }
    if (tid < 64) {
      float v = 0.0f;
#pragma unroll
      for (int r = 0; r < 16; ++r) v += Ph[r][tid];
      __hip_atomic_fetch_add(&Bg[512 + tid], v, __ATOMIC_RELAXED, AGENT);
    }
    if ((blockIdx.x >> 2) == 4) {   // blocks 16..19 zero group (blockIdx&3)
      float* nb = &ctl->B[(it + 1) % 3][blockIdx.x & 3][0];
      __hip_atomic_store(&nb[tid], 0.0f, __ATOMIC_RELAXED, AGENT);
      if (tid < 64)
        __hip_atomic_store(&nb[512 + tid], 0.0f, __ATOMIC_RELAXED, AGENT);
    }

    gridbar(ctl, bar_round);                           // s5, s6

    // === region F: finalize loads ==========================================
    const float* Bb = &ctl->B[it % 3][0][0];
    float v = Bb[tid] + Bb[kEntries + tid] + Bb[2 * kEntries + tid] +
              Bb[3 * kEntries + tid];
    if (tid < 64) {
      hhts[tid] = Bb[512 + tid] + Bb[kEntries + 512 + tid] +
                  Bb[2 * kEntries + 512 + tid] + Bb[3 * kEntries + 512 + tid];
    }
    __syncthreads();                                   // s7
    // === region G: W update (row-parallel) ================================
    float wn;
    {
      const int c0 = tid >> 3, l0 = tid & 7;
      const float4 w0 = *(const float4*)&Ws[c0][0];
      const float4 w1 = *(const float4*)&Ws[c0][4];
      float d = kEps;
      d = fmaf(w0.x, hhts[l0], d);      d = fmaf(w0.y, hhts[8 + l0], d);
      d = fmaf(w0.z, hhts[16 + l0], d); d = fmaf(w0.w, hhts[24 + l0], d);
      d = fmaf(w1.x, hhts[32 + l0], d); d = fmaf(w1.y, hhts[40 + l0], d);
      d = fmaf(w1.z, hhts[48 + l0], d); d = fmaf(w1.w, hhts[56 + l0], d);
      wn = (&Ws[0][0])[tid] * v / d;
    }
    __syncthreads();                                   // s8
    (&Ws[0][0])[tid] = wn;
    __syncthreads();                                   // s9
  }

  // ------------- epilogue ---------------------------------------------------
  float h2[2][kL];
#pragma unroll
  for (int l = 0; l < kL; ++l) {
    const float2 t2 = *(const float2*)&Hs[l][2 * p];
    h2[0][l] = t2.x; h2[1][l] = t2.y;
  }
  float errp = 0.0f;
  float vh[2][16];
#pragma unroll
  for (int ci = 0; ci < 16; ++ci) {
    const int c = obase + ci;
    const float4 w0 = *(const float4*)&Ws[c][0];
    const float4 w1 = *(const float4*)&Ws[c][4];
#pragma unroll
    for (int colx = 0; colx < 2; ++colx) {
      float t = 0.0f;
      t = fmaf(w0.x, h2[colx][0], t); t = fmaf(w0.y, h2[colx][1], t);
      t = fmaf(w0.z, h2[colx][2], t); t = fmaf(w0.w, h2[colx][3], t);
      t = fmaf(w1.x, h2[colx][4], t); t = fmaf(w1.y, h2[colx][5], t);
      t = fmaf(w1.z, h2[colx][6], t); t = fmaf(w1.w, h2[colx][7], t);
      vh[colx][ci] = t;
      const float d = vreg[colx][ci] - t;
      errp = fmaf(d, d, errp);
    }
  }
#pragma unroll
  for (int colx = 0; colx < 2; ++colx)
#pragma unroll
    for (int k = 0; k < 4; ++k)
      *(float4*)&Vt[2 * p + colx][obase + 4 * k] =
          make_float4(vh[colx][4 * k], vh[colx][4 * k + 1],
                      vh[colx][4 * k + 2], vh[colx][4 * k + 3]);
  {
    float r = errp;
#pragma unroll
    for (int off = 32; off > 0; off >>= 1) r += __shfl_down(r, off, 64);
    __syncthreads();
    if ((tid & 63) == 0) reds[tid >> 6] = r;
    __syncthreads();
    if (tid == 0) {
      float sm = 0.0f;
#pragma unroll
      for (int w = 0; w < 8; ++w) sm += reds[w];
      __hip_atomic_fetch_add(&ctl->err_sum, sm, __ATOMIC_RELAXED, AGENT);
    }
  }
  __syncthreads();
  // y = relu(W1 . vh): own 16 out-ch x 2 cols, full 64-ch input from Vt
  float ya[2][16] = {};
  for (int cb = 0; cb < 16; ++cb) {
    const float4 v0 = *(const float4*)&Vt[2 * p][cb * 4];
    const float4 v1 = *(const float4*)&Vt[2 * p + 1][cb * 4];
#pragma unroll
    for (int o = 0; o < 16; ++o) {
      const float* wr = &w_post1[(obase + o) * kC + cb * 4];
      ya[0][o] = fmaf(wr[0], v0.x, ya[0][o]); ya[1][o] = fmaf(wr[0], v1.x, ya[1][o]);
      ya[0][o] = fmaf(wr[1], v0.y, ya[0][o]); ya[1][o] = fmaf(wr[1], v1.y, ya[1][o]);
      ya[0][o] = fmaf(wr[2], v0.z, ya[0][o]); ya[1][o] = fmaf(wr[2], v1.z, ya[1][o]);
      ya[0][o] = fmaf(wr[3], v0.w, ya[0][o]); ya[1][o] = fmaf(wr[3], v1.w, ya[1][o]);
    }
  }
  __syncthreads();
#pragma unroll
  for (int colx = 0; colx < 2; ++colx)
#pragma unroll
    for (int k = 0; k < 4; ++k)
      *(float4*)&Vt[2 * p + colx][obase + 4 * k] =
          make_float4(fmaxf(ya[colx][4 * k], 0.0f), fmaxf(ya[colx][4 * k + 1], 0.0f),
                      fmaxf(ya[colx][4 * k + 2], 0.0f), fmaxf(ya[colx][4 * k + 3], 0.0f));
  __syncthreads();
  // eps_hat = W2 . y
  float oa[2][16] = {};
  for (int cb = 0; cb < 16; ++cb) {
    const float4 v0 = *(const float4*)&Vt[2 * p][cb * 4];
    const float4 v1 = *(const float4*)&Vt[2 * p + 1][cb * 4];
#pragma unroll
    for (int o = 0; o < 16; ++o) {
      const float* wr = &w_post2[(obase + o) * kC + cb * 4];
      oa[0][o] = fmaf(wr[0], v0.x, oa[0][o]); oa[1][o] = fmaf(wr[0], v1.x, oa[1][o]);
      oa[0][o] = fmaf(wr[1], v0.y, oa[0][o]); oa[1][o] = fmaf(wr[1], v1.y, oa[1][o]);
      oa[0][o] = fmaf(wr[2], v0.z, oa[0][o]); oa[1][o] = fmaf(wr[2], v1.z, oa[1][o]);
      oa[0][o] = fmaf(wr[3], v0.w, oa[0][o]); oa[1][o] = fmaf(wr[3], v1.w, oa[1][o]);
    }
  }
#pragma unroll
  for (int o = 0; o < 16; ++o)
    *(float2*)&out[(size_t)(obase + o) * kS + sb + 2 * p] =
        make_float2(oa[0][o], oa[1][o]);

  gridbar(ctl, bar_round);
  if (blockIdx.x == 0 && tid == 0)
    out[(size_t)kC * kS] =
        sqrtf(__hip_atomic_load(&ctl->err_sum, __ATOMIC_RELAXED, AGENT));
}

extern "C" void kernel_launch(void* const* d_in, const int* in_sizes, int n_in,
                              void* d_out, int out_size, void* d_ws, size_t ws_size,
                              hipStream_t stream) {
  (void)in_sizes; (void)n_in; (void)out_size; (void)ws_size;
  const float* eps     = (const float*)d_in[0];
  const float* w_pre   = (const float*)d_in[1];
  const float* b_pre   = (const float*)d_in[2];
  const float* w_post1 = (const float*)d_in[3];
  const float* w_post2 = (const float*)d_in[4];
  float* out = (float*)d_out;
  Ctl* ctl = (Ctl*)d_ws;

  init_ctl<<<64, 256, 0, stream>>>((unsigned*)d_ws);
  fsam_nmf<<<kBlocks, kThreads, 0, stream>>>(eps, w_pre, b_pre, w_post1,
                                             w_post2, out, ctl);
}

// Round 8
// 624.495 us; speedup vs baseline: 1.5250x; 1.0360x over previous
//
#include <hip/hip_runtime.h>
#include <stdint.h>

// 1 = JAX >= 0.5 default (jax_threefry_partitionable=True); 0 = legacy scheme.
#define JAX_PARTITIONABLE 1

constexpr int kC = 64;          // channels (= NMF rows T)
constexpr int kS = 65536;       // spatial 16*64*64 (= NMF cols M)
constexpr int kL = 8;           // NMF rank
constexpr int kIters = 50;
constexpr int kBlocks = 256;    // one block per CU (R4: blocks scale sync cost)
constexpr int kThreads = 512;   // R5: 1024 thr adds sync-convoy cost
constexpr int kCols = 256;      // columns per block
constexpr int kGroups = 4;      // reduction groups (64 blocks/group)
constexpr int kEntries = 576;   // 512 (VH^T) + 64 (HH^T)
constexpr int kHP = 260;        // Hs pitch
constexpr int kVP = 68;         // Vt pitch (V stored TRANSPOSED: [col][ch])
constexpr int kNP = 258;        // Pn pitch (even for float2 writes)
constexpr float kEps = 1.1920929e-07f;

#define AGENT __HIP_MEMORY_SCOPE_AGENT

struct Ctl {
  unsigned root;  unsigned pad0[31];
  unsigned leaf[16][32];                 // 16 leaf counters, 128 B apart
  float mean_sum; float err_sum; float pad1[30];
  float B[3][kGroups][kEntries];         // rotating accumulator buffers
};

__device__ __forceinline__ uint2 tf2x32(unsigned k0, unsigned k1,
                                        unsigned x0, unsigned x1) {
  unsigned k2 = k0 ^ k1 ^ 0x1BD11BDAu;
  x0 += k0; x1 += k1;
#define TF_RND(r) { x0 += x1; x1 = (x1 << (r)) | (x1 >> (32 - (r))); x1 ^= x0; }
  TF_RND(13) TF_RND(15) TF_RND(26) TF_RND(6)
  x0 += k1; x1 += k2 + 1u;
  TF_RND(17) TF_RND(29) TF_RND(16) TF_RND(24)
  x0 += k2; x1 += k0 + 2u;
  TF_RND(13) TF_RND(15) TF_RND(26) TF_RND(6)
  x0 += k0; x1 += k1 + 3u;
  TF_RND(17) TF_RND(29) TF_RND(16) TF_RND(24)
  x0 += k1; x1 += k2 + 4u;
  TF_RND(13) TF_RND(15) TF_RND(26) TF_RND(6)
  x0 += k2; x1 += k0 + 5u;
#undef TF_RND
  return make_uint2(x0, x1);
}

__device__ __forceinline__ float u01(unsigned b) {
  return __uint_as_float((b >> 9) | 0x3f800000u) - 1.0f;
}

// Two-level monotonic grid barrier (16 leaves x 16 arrivals -> 16 root).
__device__ __forceinline__ void gridbar(Ctl* ctl, unsigned& round) {
  ++round;
  __syncthreads();
  if (threadIdx.x == 0) {
    const unsigned leaf = blockIdx.x & 15u;
    unsigned a = __hip_atomic_fetch_add(&ctl->leaf[leaf][0], 1u,
                                        __ATOMIC_RELAXED, AGENT);
    if (a == round * 16u - 1u)
      __hip_atomic_fetch_add(&ctl->root, 1u, __ATOMIC_RELAXED, AGENT);
    const unsigned target = round * 16u;
    while (__hip_atomic_load(&ctl->root, __ATOMIC_RELAXED, AGENT) < target)
      __builtin_amdgcn_s_sleep(1);
    __builtin_amdgcn_fence(__ATOMIC_ACQUIRE, "agent");
  }
  __syncthreads();
}

__global__ void init_ctl(unsigned* ws) {
  const unsigned n = (unsigned)(sizeof(Ctl) / 4);
  for (unsigned i = blockIdx.x * blockDim.x + threadIdx.x; i < n;
       i += gridDim.x * blockDim.x)
    ws[i] = 0u;
}

__global__ __launch_bounds__(kThreads, 2) void fsam_nmf(
    const float* __restrict__ eps, const float* __restrict__ w_pre,
    const float* __restrict__ b_pre, const float* __restrict__ w_post1,
    const float* __restrict__ w_post2, float* __restrict__ out, Ctl* ctl) {
  __shared__ __align__(16) float Vt[kCols][kVP];    // V^T (then vhat, then y)
  __shared__ __align__(16) float Hs[kL][kHP];
  __shared__ __align__(16) float Pn[4][kL][kNP];    // phase-1 num partials
  __shared__ __align__(16) float Pv[8][512];        // VH^T range partials (swizzled)
  __shared__ __align__(16) float Ph[16][64];        // HH^T range partials (swizzled)
  __shared__ __align__(16) float Pw[8][64];         // W^T W chunk partials
  __shared__ __align__(16) float Ws[kC][kL];
  __shared__ __align__(16) float WtWs[64];
  __shared__ __align__(16) float hhts[64];
  __shared__ float reds[8];

  const int tid = threadIdx.x;
  const int g = tid >> 7;                 // channel 16-group (0..3)
  const int p = tid & 127;                // col-pair (cols 2p, 2p+1)
  const int obase = g * 16;
  const int sb = blockIdx.x * kCols;      // block's first global column
  unsigned bar_round = 0;

  // ------------- phase 0: V cols = relu(W_pre . eps + b), col-pair ---------
  float vreg[2][16];
#pragma unroll
  for (int o = 0; o < 16; ++o) { vreg[0][o] = b_pre[obase + o]; vreg[1][o] = vreg[0][o]; }
  for (int c = 0; c < kC; ++c) {
    const float2 e2 = *(const float2*)(eps + (size_t)c * kS + sb + 2 * p);
#pragma unroll
    for (int o = 0; o < 16; ++o) {
      const float w = w_pre[(obase + o) * kC + c];
      vreg[0][o] = fmaf(w, e2.x, vreg[0][o]);
      vreg[1][o] = fmaf(w, e2.y, vreg[1][o]);
    }
  }
  float lsum = 0.0f;
#pragma unroll
  for (int col = 0; col < 2; ++col) {
#pragma unroll
    for (int o = 0; o < 16; ++o) {
      vreg[col][o] = fmaxf(vreg[col][o], 0.0f);
      lsum += vreg[col][o];
    }
#pragma unroll
    for (int k = 0; k < 4; ++k)
      *(float4*)&Vt[2 * p + col][obase + 4 * k] =
          make_float4(vreg[col][4 * k], vreg[col][4 * k + 1],
                      vreg[col][4 * k + 2], vreg[col][4 * k + 3]);
  }
  {
    float r = lsum;
#pragma unroll
    for (int off = 32; off > 0; off >>= 1) r += __shfl_down(r, off, 64);
    if ((tid & 63) == 0) reds[tid >> 6] = r;
    __syncthreads();
    if (tid == 0) {
      float sm = 0.0f;
#pragma unroll
      for (int w = 0; w < 8; ++w) sm += reds[w];
      __hip_atomic_fetch_add(&ctl->mean_sum, sm, __ATOMIC_RELAXED, AGENT);
    }
  }
  gridbar(ctl, bar_round);
  const float avg = sqrtf(
      __hip_atomic_load(&ctl->mean_sum, __ATOMIC_RELAXED, AGENT) *
      (1.0f / (4194304.0f * 8.0f)));

  // ------------- threefry init (JAX-exact) ---------------------------------
#if JAX_PARTITIONABLE
  const uint2 kw = tf2x32(0u, 0u, 0u, 0u);
  const uint2 kh = tf2x32(0u, 0u, 0u, 1u);
#else
  const uint2 A0 = tf2x32(0u, 0u, 0u, 2u);
  const uint2 A1 = tf2x32(0u, 0u, 1u, 3u);
  const uint2 kw = make_uint2(A0.x, A1.x);
  const uint2 kh = make_uint2(A0.y, A1.y);
#endif
  if (tid < 256) {   // thread tid inits column tid's H
    const int s = sb + tid;
#if JAX_PARTITIONABLE
#pragma unroll
    for (int l = 0; l < kL; ++l) {
      uint2 r = tf2x32(kh.x, kh.y, 0u, (unsigned)(l * kS + s));
      Hs[l][tid] = avg * u01(r.x ^ r.y);
    }
#else
#pragma unroll
    for (int l = 0; l < 4; ++l) {
      unsigned i = (unsigned)(l * kS + s);
      uint2 r = tf2x32(kh.x, kh.y, i, i + 262144u);
      Hs[l][tid] = avg * u01(r.x);
      Hs[l + 4][tid] = avg * u01(r.y);
    }
#endif
  }
  {
#if JAX_PARTITIONABLE
    uint2 r0 = tf2x32(kw.x, kw.y, 0u, (unsigned)tid);
    (&Ws[0][0])[tid] = avg * u01(r0.x ^ r0.y);
#else
    if (tid < 256) {
      uint2 r = tf2x32(kw.x, kw.y, (unsigned)tid, (unsigned)(tid + 256));
      (&Ws[0][0])[tid] = avg * u01(r.x);
      (&Ws[0][0])[tid + 256] = avg * u01(r.y);
    }
#endif
  }
  __syncthreads();

  // ------------- 50 MU iterations ------------------------------------------
  for (int it = 0; it < kIters; ++it) {
    // === region A: W^T W chunk partials + phase-1 numerator (reads Ws) ====
    {
      const int e = tid & 63, chunk = tid >> 6, cb = chunk * 8;
      const int l = e >> 3, j = e & 7;
      float s = 0.0f;
#pragma unroll
      for (int cc = 0; cc < 8; ++cc)
        s = fmaf(Ws[cb + cc][l], Ws[cb + cc][j], s);
      Pw[chunk][e] = s;
    }
    {
      float num[2][kL] = {};
#pragma unroll
      for (int ci = 0; ci < 16; ++ci) {
        const int c = obase + ci;
        const float4 w0 = *(const float4*)&Ws[c][0];
        const float4 w1 = *(const float4*)&Ws[c][4];
        const float v0 = vreg[0][ci], v1 = vreg[1][ci];
        num[0][0] = fmaf(v0, w0.x, num[0][0]); num[0][1] = fmaf(v0, w0.y, num[0][1]);
        num[0][2] = fmaf(v0, w0.z, num[0][2]); num[0][3] = fmaf(v0, w0.w, num[0][3]);
        num[0][4] = fmaf(v0, w1.x, num[0][4]); num[0][5] = fmaf(v0, w1.y, num[0][5]);
        num[0][6] = fmaf(v0, w1.z, num[0][6]); num[0][7] = fmaf(v0, w1.w, num[0][7]);
        num[1][0] = fmaf(v1, w0.x, num[1][0]); num[1][1] = fmaf(v1, w0.y, num[1][1]);
        num[1][2] = fmaf(v1, w0.z, num[1][2]); num[1][3] = fmaf(v1, w0.w, num[1][3]);
        num[1][4] = fmaf(v1, w1.x, num[1][4]); num[1][5] = fmaf(v1, w1.y, num[1][5]);
        num[1][6] = fmaf(v1, w1.z, num[1][6]); num[1][7] = fmaf(v1, w1.w, num[1][7]);
      }
#pragma unroll
      for (int l = 0; l < kL; ++l)
        *(float2*)&Pn[g][l][2 * p] = make_float2(num[0][l], num[1][l]);
    }
    __syncthreads();                                   // s1
    // === region B: finish WtW; read h + num sums ==========================
    const int col = tid & 255, lh = tid >> 8;
    float h[kL], nm[4];
#pragma unroll
    for (int l = 0; l < kL; ++l) h[l] = Hs[l][col];
#pragma unroll
    for (int k = 0; k < 4; ++k) {
      const int l = lh * 4 + k;
      nm[k] = Pn[0][l][col] + Pn[1][l][col] + Pn[2][l][col] + Pn[3][l][col];
    }
    if (tid < 64) {
      float s = 0.0f;
#pragma unroll
      for (int r = 0; r < 8; ++r) s += Pw[r][tid];
      WtWs[tid] = s;
    }
    __syncthreads();                                   // s2
    // === region C: H update (thread = col x l-half) =======================
#pragma unroll
    for (int k = 0; k < 4; ++k) {
      const int l = lh * 4 + k;
      const float4 a = *(const float4*)&WtWs[l * kL];
      const float4 b = *(const float4*)&WtWs[l * kL + 4];
      float d = kEps;
      d = fmaf(a.x, h[0], d); d = fmaf(a.y, h[1], d);
      d = fmaf(a.z, h[2], d); d = fmaf(a.w, h[3], d);
      d = fmaf(b.x, h[4], d); d = fmaf(b.y, h[5], d);
      d = fmaf(b.z, h[6], d); d = fmaf(b.w, h[7], d);
      Hs[l][col] = h[l] * nm[k] / d;
    }
    __syncthreads();                                   // s3
    // === region D: HH^T (tid<256) + VH^T (all, transposed V) ==============
    if (tid < 256) {
      const int tle = tid & 15, rng = tid >> 4;
      const int j0 = (tle >> 2) * 2, l0 = (tle & 3) * 2;
      const int s0 = rng * 16;
      float a00 = 0, a01 = 0, a10 = 0, a11 = 0;
      for (int s4 = s0; s4 < s0 + 16; s4 += 4) {
        const float4 x0 = *(const float4*)&Hs[j0][s4];
        const float4 x1 = *(const float4*)&Hs[j0 + 1][s4];
        const float4 y0 = *(const float4*)&Hs[l0][s4];
        const float4 y1 = *(const float4*)&Hs[l0 + 1][s4];
        a00 = fmaf(x0.x, y0.x, a00); a00 = fmaf(x0.y, y0.y, a00);
        a00 = fmaf(x0.z, y0.z, a00); a00 = fmaf(x0.w, y0.w, a00);
        a01 = fmaf(x0.x, y1.x, a01); a01 = fmaf(x0.y, y1.y, a01);
        a01 = fmaf(x0.z, y1.z, a01); a01 = fmaf(x0.w, y1.w, a01);
        a10 = fmaf(x1.x, y0.x, a10); a10 = fmaf(x1.y, y0.y, a10);
        a10 = fmaf(x1.z, y0.z, a10); a10 = fmaf(x1.w, y0.w, a10);
        a11 = fmaf(x1.x, y1.x, a11); a11 = fmaf(x1.y, y1.y, a11);
        a11 = fmaf(x1.z, y1.z, a11); a11 = fmaf(x1.w, y1.w, a11);
      }
      // swizzled store: bits 0 and 3 of the slot are free in e=j0*8+l0;
      // folding rng's low bits there spreads 8-way -> 2-way (free)
      const int sw = (rng & 1) | ((rng & 2) << 2);
      Ph[rng][(j0 * 8 + l0) ^ sw] = a00;
      Ph[rng][(j0 * 8 + l0 + 1) ^ sw] = a01;
      Ph[rng][((j0 + 1) * 8 + l0) ^ sw] = a10;
      Ph[rng][((j0 + 1) * 8 + l0 + 1) ^ sw] = a11;
    }
    {
      // 64 tiles (16 c-quads x 4 l-pairs) x 8 ranges of 32 cols.
      const int tile = tid & 63, rng = tid >> 6;
      const int cq = tile & 15, lp = tile >> 4;
      const int cb = cq * 4, lb = lp * 2;
      float acc[4][2] = {};
      for (int s4 = rng * 32; s4 < rng * 32 + 32; s4 += 4) {
        const float4 h0 = *(const float4*)&Hs[lb][s4];
        const float4 h1 = *(const float4*)&Hs[lb + 1][s4];
        const float4 va = *(const float4*)&Vt[s4][cb];
        const float4 vb = *(const float4*)&Vt[s4 + 1][cb];
        const float4 vc = *(const float4*)&Vt[s4 + 2][cb];
        const float4 vd = *(const float4*)&Vt[s4 + 3][cb];
        acc[0][0] = fmaf(va.x, h0.x, acc[0][0]); acc[0][1] = fmaf(va.x, h1.x, acc[0][1]);
        acc[1][0] = fmaf(va.y, h0.x, acc[1][0]); acc[1][1] = fmaf(va.y, h1.x, acc[1][1]);
        acc[2][0] = fmaf(va.z, h0.x, acc[2][0]); acc[2][1] = fmaf(va.z, h1.x, acc[2][1]);
        acc[3][0] = fmaf(va.w, h0.x, acc[3][0]); acc[3][1] = fmaf(va.w, h1.x, acc[3][1]);
        acc[0][0] = fmaf(vb.x, h0.y, acc[0][0]); acc[0][1] = fmaf(vb.x, h1.y, acc[0][1]);
        acc[1][0] = fmaf(vb.y, h0.y, acc[1][0]); acc[1][1] = fmaf(vb.y, h1.y, acc[1][1]);
        acc[2][0] = fmaf(vb.z, h0.y, acc[2][0]); acc[2][1] = fmaf(vb.z, h1.y, acc[2][1]);
        acc[3][0] = fmaf(vb.w, h0.y, acc[3][0]); acc[3][1] = fmaf(vb.w, h1.y, acc[3][1]);
        acc[0][0] = fmaf(vc.x, h0.z, acc[0][0]); acc[0][1] = fmaf(vc.x, h1.z, acc[0][1]);
        acc[1][0] = fmaf(vc.y, h0.z, acc[1][0]); acc[1][1] = fmaf(vc.y, h1.z, acc[1][1]);
        acc[2][0] = fmaf(vc.z, h0.z, acc[2][0]); acc[2][1] = fmaf(vc.z, h1.z, acc[2][1]);
        acc[3][0] = fmaf(vc.w, h0.z, acc[3][0]); acc[3][1] = fmaf(vc.w, h1.z, acc[3][1]);
        acc[0][0] = fmaf(vd.x, h0.w, acc[0][0]); acc[0][1] = fmaf(vd.x, h1.w, acc[0][1]);
        acc[1][0] = fmaf(vd.y, h0.w, acc[1][0]); acc[1][1] = fmaf(vd.y, h1.w, acc[1][1]);
        acc[2][0] = fmaf(vd.z, h0.w, acc[2][0]); acc[2][1] = fmaf(vd.z, h1.w, acc[2][1]);
        acc[3][0] = fmaf(vd.w, h0.w, acc[3][0]); acc[3][1] = fmaf(vd.w, h1.w, acc[3][1]);
      }
      // swizzled layout: lp*128 + j*32 + ((cq ^ (j<<2) ^ lp)<<1) + b.
      // writes: each lp-group sweeps one contiguous 128 B region (free);
      // reads: XOR spreads (cq,j,lp,b) across all 32 banks (2-way, free).
#pragma unroll
      for (int j = 0; j < 4; ++j) {
        const int sl = lp * 128 + j * 32 + ((cq ^ (j << 2) ^ lp) << 1);
        *(float2*)&Pv[rng][sl] = make_float2(acc[j][0], acc[j][1]);
      }
    }
    __syncthreads();                                   // s4
    // === region E: combine + global atomics; zero next buffer =============
    float* Bg = &ctl->B[it % 3][blockIdx.x & 3][0];
    {
      const int c = tid >> 3, l = tid & 7;
      const int cq = c >> 2, j = c & 3, lp = l >> 1;
      const int slot = lp * 128 + j * 32 + ((cq ^ (j << 2) ^ lp) << 1) + (l & 1);
      float v = 0.0f;
#pragma unroll
      for (int r = 0; r < 8; ++r) v += Pv[r][slot];
      __hip_atomic_fetch_add(&Bg[tid], v, __ATOMIC_RELAXED, AGENT);
    }
    if (tid < 64) {
      float v = 0.0f;
#pragma unroll
      for (int r = 0; r < 16; ++r)
        v += Ph[r][tid ^ ((r & 1) | ((r & 2) << 2))];
      __hip_atomic_fetch_add(&Bg[512 + tid], v, __ATOMIC_RELAXED, AGENT);
    }
    if ((blockIdx.x >> 2) == 4) {   // blocks 16..19 zero group (blockIdx&3)
      float* nb = &ctl->B[(it + 1) % 3][blockIdx.x & 3][0];
      __hip_atomic_store(&nb[tid], 0.0f, __ATOMIC_RELAXED, AGENT);
      if (tid < 64)
        __hip_atomic_store(&nb[512 + tid], 0.0f, __ATOMIC_RELAXED, AGENT);
    }

    gridbar(ctl, bar_round);                           // s5, s6

    // === region F: finalize loads ==========================================
    const float* Bb = &ctl->B[it % 3][0][0];
    float v = Bb[tid] + Bb[kEntries + tid] + Bb[2 * kEntries + tid] +
              Bb[3 * kEntries + tid];
    if (tid < 64) {
      hhts[tid] = Bb[512 + tid] + Bb[kEntries + 512 + tid] +
                  Bb[2 * kEntries + 512 + tid] + Bb[3 * kEntries + 512 + tid];
    }
    __syncthreads();                                   // s7
    // === region G: W update (row-parallel) ================================
    float wn;
    {
      const int c0 = tid >> 3, l0 = tid & 7;
      const float4 w0 = *(const float4*)&Ws[c0][0];
      const float4 w1 = *(const float4*)&Ws[c0][4];
      float d = kEps;
      d = fmaf(w0.x, hhts[l0], d);      d = fmaf(w0.y, hhts[8 + l0], d);
      d = fmaf(w0.z, hhts[16 + l0], d); d = fmaf(w0.w, hhts[24 + l0], d);
      d = fmaf(w1.x, hhts[32 + l0], d); d = fmaf(w1.y, hhts[40 + l0], d);
      d = fmaf(w1.z, hhts[48 + l0], d); d = fmaf(w1.w, hhts[56 + l0], d);
      wn = (&Ws[0][0])[tid] * v / d;
    }
    __syncthreads();                                   // s8
    (&Ws[0][0])[tid] = wn;
    __syncthreads();                                   // s9
  }

  // ------------- epilogue ---------------------------------------------------
  float h2[2][kL];
#pragma unroll
  for (int l = 0; l < kL; ++l) {
    const float2 t2 = *(const float2*)&Hs[l][2 * p];
    h2[0][l] = t2.x; h2[1][l] = t2.y;
  }
  float errp = 0.0f;
  float vh[2][16];
#pragma unroll
  for (int ci = 0; ci < 16; ++ci) {
    const int c = obase + ci;
    const float4 w0 = *(const float4*)&Ws[c][0];
    const float4 w1 = *(const float4*)&Ws[c][4];
#pragma unroll
    for (int colx = 0; colx < 2; ++colx) {
      float t = 0.0f;
      t = fmaf(w0.x, h2[colx][0], t); t = fmaf(w0.y, h2[colx][1], t);
      t = fmaf(w0.z, h2[colx][2], t); t = fmaf(w0.w, h2[colx][3], t);
      t = fmaf(w1.x, h2[colx][4], t); t = fmaf(w1.y, h2[colx][5], t);
      t = fmaf(w1.z, h2[colx][6], t); t = fmaf(w1.w, h2[colx][7], t);
      vh[colx][ci] = t;
      const float d = vreg[colx][ci] - t;
      errp = fmaf(d, d, errp);
    }
  }
#pragma unroll
  for (int colx = 0; colx < 2; ++colx)
#pragma unroll
    for (int k = 0; k < 4; ++k)
      *(float4*)&Vt[2 * p + colx][obase + 4 * k] =
          make_float4(vh[colx][4 * k], vh[colx][4 * k + 1],
                      vh[colx][4 * k + 2], vh[colx][4 * k + 3]);
  {
    float r = errp;
#pragma unroll
    for (int off = 32; off > 0; off >>= 1) r += __shfl_down(r, off, 64);
    __syncthreads();
    if ((tid & 63) == 0) reds[tid >> 6] = r;
    __syncthreads();
    if (tid == 0) {
      float sm = 0.0f;
#pragma unroll
      for (int w = 0; w < 8; ++w) sm += reds[w];
      __hip_atomic_fetch_add(&ctl->err_sum, sm, __ATOMIC_RELAXED, AGENT);
    }
  }
  __syncthreads();
  // y = relu(W1 . vh): own 16 out-ch x 2 cols, full 64-ch input from Vt
  float ya[2][16] = {};
  for (int cb = 0; cb < 16; ++cb) {
    const float4 v0 = *(const float4*)&Vt[2 * p][cb * 4];
    const float4 v1 = *(const float4*)&Vt[2 * p + 1][cb * 4];
#pragma unroll
    for (int o = 0; o < 16; ++o) {
      const float* wr = &w_post1[(obase + o) * kC + cb * 4];
      ya[0][o] = fmaf(wr[0], v0.x, ya[0][o]); ya[1][o] = fmaf(wr[0], v1.x, ya[1][o]);
      ya[0][o] = fmaf(wr[1], v0.y, ya[0][o]); ya[1][o] = fmaf(wr[1], v1.y, ya[1][o]);
      ya[0][o] = fmaf(wr[2], v0.z, ya[0][o]); ya[1][o] = fmaf(wr[2], v1.z, ya[1][o]);
      ya[0][o] = fmaf(wr[3], v0.w, ya[0][o]); ya[1][o] = fmaf(wr[3], v1.w, ya[1][o]);
    }
  }
  __syncthreads();
#pragma unroll
  for (int colx = 0; colx < 2; ++colx)
#pragma unroll
    for (int k = 0; k < 4; ++k)
      *(float4*)&Vt[2 * p + colx][obase + 4 * k] =
          make_float4(fmaxf(ya[colx][4 * k], 0.0f), fmaxf(ya[colx][4 * k + 1], 0.0f),
                      fmaxf(ya[colx][4 * k + 2], 0.0f), fmaxf(ya[colx][4 * k + 3], 0.0f));
  __syncthreads();
  // eps_hat = W2 . y
  float oa[2][16] = {};
  for (int cb = 0; cb < 16; ++cb) {
    const float4 v0 = *(const float4*)&Vt[2 * p][cb * 4];
    const float4 v1 = *(const float4*)&Vt[2 * p + 1][cb * 4];
#pragma unroll
    for (int o = 0; o < 16; ++o) {
      const float* wr = &w_post2[(obase + o) * kC + cb * 4];
      oa[0][o] = fmaf(wr[0], v0.x, oa[0][o]); oa[1][o] = fmaf(wr[0], v1.x, oa[1][o]);
      oa[0][o] = fmaf(wr[1], v0.y, oa[0][o]); oa[1][o] = fmaf(wr[1], v1.y, oa[1][o]);
      oa[0][o] = fmaf(wr[2], v0.z, oa[0][o]); oa[1][o] = fmaf(wr[2], v1.z, oa[1][o]);
      oa[0][o] = fmaf(wr[3], v0.w, oa[0][o]); oa[1][o] = fmaf(wr[3], v1.w, oa[1][o]);
    }
  }
#pragma unroll
  for (int o = 0; o < 16; ++o)
    *(float2*)&out[(size_t)(obase + o) * kS + sb + 2 * p] =
        make_float2(oa[0][o], oa[1][o]);

  gridbar(ctl, bar_round);
  if (blockIdx.x == 0 && tid == 0)
    out[(size_t)kC * kS] =
        sqrtf(__hip_atomic_load(&ctl->err_sum, __ATOMIC_RELAXED, AGENT));
}

extern "C" void kernel_launch(void* const* d_in, const int* in_sizes, int n_in,
                              void* d_out, int out_size, void* d_ws, size_t ws_size,
                              hipStream_t stream) {
  (void)in_sizes; (void)n_in; (void)out_size; (void)ws_size;
  const float* eps     = (const float*)d_in[0];
  const float* w_pre   = (const float*)d_in[1];
  const float* b_pre   = (const float*)d_in[2];
  const float* w_post1 = (const float*)d_in[3];
  const float* w_post2 = (const float*)d_in[4];
  float* out = (float*)d_out;
  Ctl* ctl = (Ctl*)d_ws;

  init_ctl<<<64, 256, 0, stream>>>((unsigned*)d_ws);
  fsam_nmf<<<kBlocks, kThreads, 0, stream>>>(eps, w_pre, b_pre, w_post1,
                                             w_post2, out, ctl);
}